// Round 6
// baseline (292.095 us; speedup 1.0000x reference)
//
#include <hip/hip_runtime.h>
#include <hip/hip_bf16.h>

using u16 = unsigned short;
typedef float f32x4 __attribute__((ext_vector_type(4)));
typedef __bf16 bf16x8 __attribute__((ext_vector_type(8)));

#define T_SEQ 2048
#define C_DIM 2048
#define QKV_DIM 3072
#define N_HEAD 32
#define N_GROUPS 8
#define HEAD_SIZE 64
#define ROPE_N 16
#define NEG_BIG (-1e30f)
#define LS 72    // flash LDS row stride
#define GS 40    // gemm LDS row stride (u16): 80B, 16B-aligned rows, 2-way max conflict

__device__ inline float bf2f(u16 u) {
    union { float f; unsigned v; } x; x.v = ((unsigned)u) << 16; return x.f;
}
__device__ inline u16 f2bf(float f) {   // hardware RNE cvt on gfx950
    __bf16 h = (__bf16)f;
    return *(u16*)&h;
}
// pack 8 fp32 (two int4 reg blocks) -> 8 bf16 (one int4)
__device__ inline int4 cvt8(int4 lo, int4 hi) {
    const float* fa = (const float*)&lo;
    const float* fb = (const float*)&hi;
    __attribute__((aligned(16))) u16 o[8] = {
        f2bf(fa[0]), f2bf(fa[1]), f2bf(fa[2]), f2bf(fa[3]),
        f2bf(fb[0]), f2bf(fb[1]), f2bf(fb[2]), f2bf(fb[3]) };
    return *(const int4*)o;
}

// ---------------------------------------------------------------------------
// Dtype probe: fp32 data read as bf16 shows ~uniform exponent bits (|v|>=2^65)
// ---------------------------------------------------------------------------
__global__ void detect_dtype(const u16* __restrict__ x, int* __restrict__ flag)
{
    __shared__ int s[256];
    int cnt = 0;
    for (int i = threadIdx.x; i < 8192; i += 256) {
        int e = (x[i] >> 7) & 0xFF;
        cnt += (e >= 0xC0);
    }
    s[threadIdx.x] = cnt;
    __syncthreads();
    if (threadIdx.x == 0) {
        int tot = 0;
        for (int i = 0; i < 256; i++) tot += s[i];
        flag[0] = (tot > 64) ? 1 : 0;
    }
}

// ---------------------------------------------------------------------------
// Converter for the 4 SMALL tensors (cos, sin, b_attn, b_proj). Big tensors
// (x, W_attn, W_proj) are converted inside the GEMM staging path.
// ---------------------------------------------------------------------------
struct ConvDesc {
    const void* src[4];
    u16*        dst[4];
    int         off8[5];
};

__global__ void convert_small(ConvDesc cd, const int* __restrict__ flag)
{
    int gid = blockIdx.x * blockDim.x + threadIdx.x;
    if (gid >= cd.off8[4]) return;
    int seg = 0;
#pragma unroll
    for (int s = 1; s < 4; s++) seg += (gid >= cd.off8[s]);
    int i = (gid - cd.off8[seg]) * 8;
    if (*flag) {
        const float4* s = (const float4*)((const float*)cd.src[seg] + i);
        *(int4*)(cd.dst[seg] + i) = cvt8(*(const int4*)&s[0], *(const int4*)&s[1]);
    } else {
        *(int4*)(cd.dst[seg] + i) = *(const int4*)((const u16*)cd.src[seg] + i);
    }
}

// ---------------------------------------------------------------------------
// GEMM1 + RoPE/scatter epilogue. 64(M)x128(N), BK=32. Register-pipelined,
// LDS double-buffered, ONE barrier per K-step: loads for tile k+1 are issued
// right after the barrier and stay in flight across the MFMA phase (the
// m97-structure vmcnt(0)-drain stall is what capped R5 at MfmaUtil 13%).
// A and W are raw inputs (fp32 or bf16 per *flag); converted during staging.
// ---------------------------------------------------------------------------
__global__ __launch_bounds__(256) void gemm_qkv_rope(
    const void* __restrict__ A, const void* __restrict__ W,
    const u16* __restrict__ bias,
    const u16* __restrict__ ccos, const u16* __restrict__ csin,
    u16* __restrict__ Qout, u16* __restrict__ Kout, u16* __restrict__ Vtout,
    const int* __restrict__ flag)
{
    __shared__ __attribute__((aligned(16))) u16 lds_a[2][64 * GS];
    __shared__ __attribute__((aligned(16))) u16 lds_b[2][128 * GS];

    const int tid  = threadIdx.x;
    const int wave = tid >> 6;
    const int lane = tid & 63;
    const int quad = lane >> 4;
    const int l16  = lane & 15;
    const int bm = blockIdx.y * 64;
    const int bn = blockIdx.x * 128;
    const int K = C_DIM;
    const int fl = *flag;

    f32x4 acc[4][2] = {};

    // staging slots: A 256 (tid), B 512 (tid, tid+256); slot s -> row s>>2, col (s&3)*8
    const int ra = tid >> 2, ca = (tid & 3) * 8;
    const int rb1 = ra + 64;

    int4 ap[2], bp0[2], bp1[2];
    auto load_tile = [&](int k0) {
        size_t ea  = (size_t)(bm + ra) * K + k0 + ca;
        size_t eb0 = (size_t)(bn + ra) * K + k0 + ca;
        size_t eb1 = (size_t)(bn + rb1) * K + k0 + ca;
        if (fl) {
            const float* Af = (const float*)A; const float* Wf = (const float*)W;
            ap[0]  = *(const int4*)(Af + ea);  ap[1]  = *(const int4*)(Af + ea + 4);
            bp0[0] = *(const int4*)(Wf + eb0); bp0[1] = *(const int4*)(Wf + eb0 + 4);
            bp1[0] = *(const int4*)(Wf + eb1); bp1[1] = *(const int4*)(Wf + eb1 + 4);
        } else {
            const u16* Ab = (const u16*)A; const u16* Wb = (const u16*)W;
            ap[0]  = *(const int4*)(Ab + ea);
            bp0[0] = *(const int4*)(Wb + eb0);
            bp1[0] = *(const int4*)(Wb + eb1);
        }
    };

    load_tile(0);
    const int nsteps = K / 32;
    for (int kt = 0; kt < nsteps; kt++) {
        const int p = kt & 1;
        int4 av  = fl ? cvt8(ap[0], ap[1])  : ap[0];
        int4 bv0 = fl ? cvt8(bp0[0], bp0[1]) : bp0[0];
        int4 bv1 = fl ? cvt8(bp1[0], bp1[1]) : bp1[0];
        *(int4*)(lds_a[p] + ra * GS + ca)  = av;
        *(int4*)(lds_b[p] + ra * GS + ca)  = bv0;
        *(int4*)(lds_b[p] + rb1 * GS + ca) = bv1;
        __syncthreads();
        if (kt + 1 < nsteps) load_tile((kt + 1) * 32);  // in flight during MFMA

        bf16x8 afr[4], bfr[2];
#pragma unroll
        for (int i = 0; i < 4; i++)
            afr[i] = *(const bf16x8*)(lds_a[p] + (i * 16 + l16) * GS + quad * 8);
#pragma unroll
        for (int j = 0; j < 2; j++)
            bfr[j] = *(const bf16x8*)(lds_b[p] + (wave * 32 + j * 16 + l16) * GS + quad * 8);
#pragma unroll
        for (int i = 0; i < 4; i++)
#pragma unroll
            for (int j = 0; j < 2; j++)
                acc[i][j] = __builtin_amdgcn_mfma_f32_16x16x32_bf16(afr[i], bfr[j], acc[i][j], 0, 0, 0);
    }

    // epilogue: bias + RoPE + scatter
#pragma unroll
    for (int j = 0; j < 2; j++) {
        const int colb = bn + wave * 32 + j * 16;      // wave-uniform
        const int col  = colb + l16;
        const int slot = (colb % 384) >> 6;            // 0..3 q, 4 k, 5 v
        const int g    = colb / 384;
        const int dbase = colb & 63;
        const int d    = dbase + l16;
        const float bv = bf2f(bias[col]);
        const bool rope = (dbase == 0) && (slot != 5);
#pragma unroll
        for (int i = 0; i < 4; i++) {
            const int trow = bm + i * 16 + quad * 4;
#pragma unroll
            for (int r = 0; r < 4; r++) {
                float v = acc[i][j][r] + bv;
                float outv = v;
                if (rope) {
                    float part = __shfl_xor(v, 8, 64);
                    float rot = (l16 < 8) ? -part : part;
                    float cc = bf2f(ccos[(trow + r) * ROPE_N + l16]);
                    float ss = bf2f(csin[(trow + r) * ROPE_N + l16]);
                    outv = v * cc + rot * ss;
                }
                const int t = trow + r;
                if (slot < 4) {
                    int hh = g * 4 + slot;
                    Qout[((size_t)hh * T_SEQ + t) * 64 + d] = f2bf(outv * 0.125f);
                } else if (slot == 4) {
                    Kout[((size_t)g * T_SEQ + t) * 64 + d] = f2bf(outv);
                } else {
                    Vtout[((size_t)g * 64 + d) * T_SEQ + t] = f2bf(outv);
                }
            }
        }
    }
}

// ---------------------------------------------------------------------------
// GEMM2: out = A @ W^T + bias. A is internal bf16 (Yb); W raw (fp32/bf16 per
// flag); store dtype follows flag. Same register-pipeline structure.
// ---------------------------------------------------------------------------
__global__ __launch_bounds__(256) void gemm_bt(
    const u16* __restrict__ A, const void* __restrict__ W,
    const u16* __restrict__ bias, u16* __restrict__ Cout,
    int M, int N, int K, const int* __restrict__ flag)
{
    __shared__ __attribute__((aligned(16))) u16 lds_a[2][64 * GS];
    __shared__ __attribute__((aligned(16))) u16 lds_b[2][128 * GS];

    const int tid  = threadIdx.x;
    const int wave = tid >> 6;
    const int lane = tid & 63;
    const int quad = lane >> 4;
    const int l16  = lane & 15;
    const int bm = blockIdx.y * 64;
    const int bn = blockIdx.x * 128;
    const int fl = *flag;

    f32x4 acc[4][2] = {};

    const int ra = tid >> 2, ca = (tid & 3) * 8;
    const int rb1 = ra + 64;

    int4 ap, bp0[2], bp1[2];
    auto load_tile = [&](int k0) {
        size_t ea  = (size_t)(bm + ra) * K + k0 + ca;
        size_t eb0 = (size_t)(bn + ra) * K + k0 + ca;
        size_t eb1 = (size_t)(bn + rb1) * K + k0 + ca;
        ap = *(const int4*)(A + ea);
        if (fl) {
            const float* Wf = (const float*)W;
            bp0[0] = *(const int4*)(Wf + eb0); bp0[1] = *(const int4*)(Wf + eb0 + 4);
            bp1[0] = *(const int4*)(Wf + eb1); bp1[1] = *(const int4*)(Wf + eb1 + 4);
        } else {
            const u16* Wb = (const u16*)W;
            bp0[0] = *(const int4*)(Wb + eb0);
            bp1[0] = *(const int4*)(Wb + eb1);
        }
    };

    load_tile(0);
    const int nsteps = K / 32;
    for (int kt = 0; kt < nsteps; kt++) {
        const int p = kt & 1;
        int4 bv0 = fl ? cvt8(bp0[0], bp0[1]) : bp0[0];
        int4 bv1 = fl ? cvt8(bp1[0], bp1[1]) : bp1[0];
        *(int4*)(lds_a[p] + ra * GS + ca)  = ap;
        *(int4*)(lds_b[p] + ra * GS + ca)  = bv0;
        *(int4*)(lds_b[p] + rb1 * GS + ca) = bv1;
        __syncthreads();
        if (kt + 1 < nsteps) load_tile((kt + 1) * 32);

        bf16x8 afr[4], bfr[2];
#pragma unroll
        for (int i = 0; i < 4; i++)
            afr[i] = *(const bf16x8*)(lds_a[p] + (i * 16 + l16) * GS + quad * 8);
#pragma unroll
        for (int j = 0; j < 2; j++)
            bfr[j] = *(const bf16x8*)(lds_b[p] + (wave * 32 + j * 16 + l16) * GS + quad * 8);
#pragma unroll
        for (int i = 0; i < 4; i++)
#pragma unroll
            for (int j = 0; j < 2; j++)
                acc[i][j] = __builtin_amdgcn_mfma_f32_16x16x32_bf16(afr[i], bfr[j], acc[i][j], 0, 0, 0);
    }

#pragma unroll
    for (int i = 0; i < 4; i++) {
        int row = bm + i * 16 + quad * 4;
#pragma unroll
        for (int j = 0; j < 2; j++) {
            int col = bn + wave * 32 + j * 16 + l16;
            float bv = bf2f(bias[col]);
#pragma unroll
            for (int r = 0; r < 4; r++) {
                float v = acc[i][j][r] + bv;
                size_t idx = (size_t)(row + r) * N + col;
                if (fl) ((float*)Cout)[idx] = v;
                else    Cout[idx] = f2bf(v);
            }
        }
    }
}

// ---------------------------------------------------------------------------
// Flash attention: fixed-max softmax, diagonal-only masking, LDS-dbuf K/Vt
// with register prefetch. Grid (16,32): block bx does q-tiles {bx, 31-bx}.
// ---------------------------------------------------------------------------
__global__ __launch_bounds__(256) void flash_attn(
    const u16* __restrict__ Q, const u16* __restrict__ K,
    const u16* __restrict__ Vt, u16* __restrict__ Y)
{
    __shared__ __attribute__((aligned(16))) u16 lds_q[64 * LS];
    __shared__ __attribute__((aligned(16))) u16 lds_k[2][64 * LS];
    __shared__ __attribute__((aligned(16))) u16 lds_vt[2][64 * LS];
    __shared__ __attribute__((aligned(16))) u16 lds_p[4][16 * LS];

    const int h  = blockIdx.y;
    const int g  = h >> 2;
    const int tid  = threadIdx.x;
    const int wave = tid >> 6;
    const int lane = tid & 63;
    const int quad = lane >> 4;
    const int l16  = lane & 15;
    const int NQT = T_SEQ / 64;

    const u16* Qh = Q  + (size_t)h * T_SEQ * 64;
    const u16* Kg = K  + (size_t)g * T_SEQ * 64;
    const u16* Vg = Vt + (size_t)g * 64 * T_SEQ;   // [d][T]

    const int srow = tid >> 3, scc = (tid & 7) * 8;

    int4 kr0, kr1, vr0, vr1;
    auto load_tile = [&](int k0) {
        kr0 = *(const int4*)(Kg + (size_t)(k0 + srow) * 64 + scc);
        kr1 = *(const int4*)(Kg + (size_t)(k0 + srow + 32) * 64 + scc);
        vr0 = *(const int4*)(Vg + (size_t)srow * T_SEQ + k0 + scc);
        vr1 = *(const int4*)(Vg + (size_t)(srow + 32) * T_SEQ + k0 + scc);
    };

    for (int pass = 0; pass < 2; pass++) {
        const int qt = pass ? (NQT - 1 - blockIdx.x) : blockIdx.x;
        const int q0 = qt * 64;

        __syncthreads();
        for (int s = tid; s < 512; s += 256) {
            int row = s >> 3, cc = (s & 7) * 8;
            *(int4*)(lds_q + row * LS + cc) =
                *(const int4*)(Qh + (size_t)(q0 + row) * 64 + cc);
        }
        __syncthreads();

        bf16x8 a_q[2];
#pragma unroll
        for (int ks = 0; ks < 2; ks++)
            a_q[ks] = *(const bf16x8*)(lds_q + (wave * 16 + l16) * LS + ks * 32 + quad * 8);

        float rs[4] = {0.f, 0.f, 0.f, 0.f};
        f32x4 o_acc[4] = {};

        load_tile(0);

        for (int kt = 0; kt <= qt; kt++) {
            const int p = kt & 1;
            *(int4*)(lds_k[p]  + srow * LS + scc)        = kr0;
            *(int4*)(lds_k[p]  + (srow + 32) * LS + scc) = kr1;
            *(int4*)(lds_vt[p] + srow * LS + scc)        = vr0;
            *(int4*)(lds_vt[p] + (srow + 32) * LS + scc) = vr1;
            __syncthreads();
            if (kt < qt) load_tile((kt + 1) * 64);

            f32x4 sc[4] = {};
#pragma unroll
            for (int ks = 0; ks < 2; ks++)
#pragma unroll
                for (int t = 0; t < 4; t++) {
                    bf16x8 bk = *(const bf16x8*)(lds_k[p] + (t * 16 + l16) * LS + ks * 32 + quad * 8);
                    sc[t] = __builtin_amdgcn_mfma_f32_16x16x32_bf16(a_q[ks], bk, sc[t], 0, 0, 0);
                }

            if (kt == qt) {
                const int row_g = q0 + wave * 16 + quad * 4;
                const int k0 = kt * 64;
#pragma unroll
                for (int t = 0; t < 4; t++) {
                    int col_g = k0 + t * 16 + l16;
#pragma unroll
                    for (int r = 0; r < 4; r++)
                        if (col_g > row_g + r) sc[t][r] = NEG_BIG;
                }
            }

#pragma unroll
            for (int t = 0; t < 4; t++) {
                int colo = t * 16 + l16;
#pragma unroll
                for (int r = 0; r < 4; r++) {
                    float pv = __expf(sc[t][r]);
                    rs[r] += pv;
                    lds_p[wave][(quad * 4 + r) * LS + colo] = f2bf(pv);
                }
            }
            __syncthreads();

#pragma unroll
            for (int ks = 0; ks < 2; ks++) {
                bf16x8 apf = *(const bf16x8*)(lds_p[wave] + l16 * LS + ks * 32 + quad * 8);
#pragma unroll
                for (int t = 0; t < 4; t++) {
                    bf16x8 bvf = *(const bf16x8*)(lds_vt[p] + (t * 16 + l16) * LS + ks * 32 + quad * 8);
                    o_acc[t] = __builtin_amdgcn_mfma_f32_16x16x32_bf16(apf, bvf, o_acc[t], 0, 0, 0);
                }
            }
        }

#pragma unroll
        for (int off = 1; off < 16; off <<= 1)
#pragma unroll
            for (int r = 0; r < 4; r++)
                rs[r] += __shfl_xor(rs[r], off, 64);

#pragma unroll
        for (int t = 0; t < 4; t++)
#pragma unroll
            for (int r = 0; r < 4; r++) {
                int row = q0 + wave * 16 + quad * 4 + r;
                int d   = t * 16 + l16;
                Y[(size_t)row * (N_HEAD * HEAD_SIZE) + h * 64 + d] = f2bf(o_acc[t][r] / rs[r]);
            }
    }
}

// ---------------------------------------------------------------------------
extern "C" void kernel_launch(void* const* d_in, const int* in_sizes, int n_in,
                              void* d_out, int out_size, void* d_ws, size_t ws_size,
                              hipStream_t stream)
{
    int* flag = (int*)d_ws;
    u16* base = (u16*)d_ws + 8;

    u16* cba  = base;                                      // 3072
    u16* cbp  = cba + QKV_DIM;                             // 2048
    u16* ccos = cbp + C_DIM;                               // 2048*16
    u16* csin = ccos + (size_t)T_SEQ * ROPE_N;             // 2048*16
    u16* Qb   = csin + (size_t)T_SEQ * ROPE_N;             // 32*2048*64
    u16* Kb   = Qb + (size_t)N_HEAD * T_SEQ * HEAD_SIZE;   // 8*2048*64
    u16* Vtb  = Kb + (size_t)N_GROUPS * T_SEQ * HEAD_SIZE; // 8*64*2048 (transposed)
    u16* Yb   = Vtb + (size_t)N_GROUPS * T_SEQ * HEAD_SIZE;// 2048*2048

    dim3 blk(256);

    detect_dtype<<<1, blk, 0, stream>>>((const u16*)d_in[0], flag);

    ConvDesc cd;
    const int sizes[4] = { T_SEQ * ROPE_N, T_SEQ * ROPE_N, QKV_DIM, C_DIM };
    const void* srcs[4] = { d_in[1], d_in[2], d_in[4], d_in[6] };
    u16* dsts[4] = { ccos, csin, cba, cbp };
    int acc8 = 0;
    for (int i = 0; i < 4; i++) {
        cd.src[i] = srcs[i];
        cd.dst[i] = dsts[i];
        cd.off8[i] = acc8;
        acc8 += sizes[i] / 8;
    }
    cd.off8[4] = acc8;
    convert_small<<<dim3((acc8 + 255) / 256), blk, 0, stream>>>(cd, flag);

    gemm_qkv_rope<<<dim3(QKV_DIM / 128, T_SEQ / 64), blk, 0, stream>>>(
        d_in[0], d_in[3], cba, ccos, csin, Qb, Kb, Vtb, flag);
    flash_attn<<<dim3(T_SEQ / 128, N_HEAD), blk, 0, stream>>>(Qb, Kb, Vtb, Yb);
    gemm_bt<<<dim3(C_DIM / 128, T_SEQ / 64), blk, 0, stream>>>(
        Yb, d_in[5], cbp, (u16*)d_out, T_SEQ, C_DIM, N_HEAD * HEAD_SIZE, flag);
}

// Round 7
// 270.860 us; speedup vs baseline: 1.0784x; 1.0784x over previous
//
#include <hip/hip_runtime.h>
#include <hip/hip_bf16.h>

using u16 = unsigned short;
typedef float f32x4 __attribute__((ext_vector_type(4)));
typedef __bf16 bf16x8 __attribute__((ext_vector_type(8)));

#define T_SEQ 2048
#define C_DIM 2048
#define QKV_DIM 3072
#define N_HEAD 32
#define N_GROUPS 8
#define HEAD_SIZE 64
#define ROPE_N 16
#define NEG_BIG (-1e30f)
#define LS 72    // flash LDS row stride
#define GS 40    // gemm LDS row stride (u16): 80B rows, 16B-aligned, ~2-way max conflict

__device__ inline float bf2f(u16 u) {
    union { float f; unsigned v; } x; x.v = ((unsigned)u) << 16; return x.f;
}
__device__ inline u16 f2bf(float f) {   // hardware RNE cvt on gfx950
    __bf16 h = (__bf16)f;
    return *(u16*)&h;
}
// pack 8 fp32 (two int4 reg blocks) -> 8 bf16 (one int4)
__device__ inline int4 cvt8(int4 lo, int4 hi) {
    const float* fa = (const float*)&lo;
    const float* fb = (const float*)&hi;
    __attribute__((aligned(16))) u16 o[8] = {
        f2bf(fa[0]), f2bf(fa[1]), f2bf(fa[2]), f2bf(fa[3]),
        f2bf(fb[0]), f2bf(fb[1]), f2bf(fb[2]), f2bf(fb[3]) };
    return *(const int4*)o;
}

// ---------------------------------------------------------------------------
// Dtype probe: fp32 data read as bf16 shows ~uniform exponent bits (|v|>=2^65)
// ---------------------------------------------------------------------------
__global__ void detect_dtype(const u16* __restrict__ x, int* __restrict__ flag)
{
    __shared__ int s[256];
    int cnt = 0;
    for (int i = threadIdx.x; i < 8192; i += 256) {
        int e = (x[i] >> 7) & 0xFF;
        cnt += (e >= 0xC0);
    }
    s[threadIdx.x] = cnt;
    __syncthreads();
    if (threadIdx.x == 0) {
        int tot = 0;
        for (int i = 0; i < 256; i++) tot += s[i];
        flag[0] = (tot > 64) ? 1 : 0;
    }
}

// ---------------------------------------------------------------------------
// Fused converter: ALL 7 inputs -> bf16 in one launch (8 elems/thread).
// Convert-once is the right trade: GEMM blocks re-read A 24x and W 32x, so
// reading raw fp32 in-staging doubles FETCH (R6: 40->78 MB, +37 us).
// ---------------------------------------------------------------------------
struct ConvDesc {
    const void* src[7];
    u16*        dst[7];
    int         off8[8];   // cumulative size/8 boundaries
};

__global__ void convert_all(ConvDesc cd, const int* __restrict__ flag)
{
    int gid = blockIdx.x * blockDim.x + threadIdx.x;  // 8-elem chunk index
    if (gid >= cd.off8[7]) return;
    int seg = 0;
#pragma unroll
    for (int s = 1; s < 7; s++) seg += (gid >= cd.off8[s]);
    int i = (gid - cd.off8[seg]) * 8;
    if (*flag) {
        const float4* s = (const float4*)((const float*)cd.src[seg] + i);
        *(int4*)(cd.dst[seg] + i) = cvt8(*(const int4*)&s[0], *(const int4*)&s[1]);
    } else {
        *(int4*)(cd.dst[seg] + i) = *(const int4*)((const u16*)cd.src[seg] + i);
    }
}

// ---------------------------------------------------------------------------
// GEMM1 + RoPE/scatter epilogue. 64(M)x128(N), BK=32, bf16 inputs.
// Single-barrier register-pipelined K-loop: tile k+1's global loads are
// issued right after the barrier and stay in flight across the MFMA phase;
// results land in LDS at the top of the next iteration. One barrier/step.
// ---------------------------------------------------------------------------
__global__ __launch_bounds__(256) void gemm_qkv_rope(
    const u16* __restrict__ A, const u16* __restrict__ W,
    const u16* __restrict__ bias,
    const u16* __restrict__ ccos, const u16* __restrict__ csin,
    u16* __restrict__ Qout, u16* __restrict__ Kout, u16* __restrict__ Vtout)
{
    __shared__ __attribute__((aligned(16))) u16 lds_a[2][64 * GS];
    __shared__ __attribute__((aligned(16))) u16 lds_b[2][128 * GS];

    const int tid  = threadIdx.x;
    const int wave = tid >> 6;
    const int lane = tid & 63;
    const int quad = lane >> 4;
    const int l16  = lane & 15;
    const int bm = blockIdx.y * 64;
    const int bn = blockIdx.x * 128;
    const int K = C_DIM;

    f32x4 acc[4][2] = {};

    // staging: slot s -> row s>>2, k-chunk (s&3)*8
    const int ra = tid >> 2, ca = (tid & 3) * 8;
    const int rb1 = ra + 64;

    int4 ap, bp0, bp1;
    auto load_tile = [&](int k0) {
        ap  = *(const int4*)(A + (size_t)(bm + ra) * K + k0 + ca);
        bp0 = *(const int4*)(W + (size_t)(bn + ra) * K + k0 + ca);
        bp1 = *(const int4*)(W + (size_t)(bn + rb1) * K + k0 + ca);
    };

    load_tile(0);
    const int nsteps = K / 32;
    for (int kt = 0; kt < nsteps; kt++) {
        const int p = kt & 1;
        *(int4*)(lds_a[p] + ra * GS + ca)  = ap;
        *(int4*)(lds_b[p] + ra * GS + ca)  = bp0;
        *(int4*)(lds_b[p] + rb1 * GS + ca) = bp1;
        __syncthreads();
        if (kt + 1 < nsteps) load_tile((kt + 1) * 32);  // in flight during MFMA

        bf16x8 afr[4], bfr[2];
#pragma unroll
        for (int i = 0; i < 4; i++)
            afr[i] = *(const bf16x8*)(lds_a[p] + (i * 16 + l16) * GS + quad * 8);
#pragma unroll
        for (int j = 0; j < 2; j++)
            bfr[j] = *(const bf16x8*)(lds_b[p] + (wave * 32 + j * 16 + l16) * GS + quad * 8);
#pragma unroll
        for (int i = 0; i < 4; i++)
#pragma unroll
            for (int j = 0; j < 2; j++)
                acc[i][j] = __builtin_amdgcn_mfma_f32_16x16x32_bf16(afr[i], bfr[j], acc[i][j], 0, 0, 0);
    }

    // epilogue: bias + RoPE + scatter
#pragma unroll
    for (int j = 0; j < 2; j++) {
        const int colb = bn + wave * 32 + j * 16;      // wave-uniform
        const int col  = colb + l16;
        const int slot = (colb % 384) >> 6;            // 0..3 q, 4 k, 5 v
        const int g    = colb / 384;
        const int dbase = colb & 63;
        const int d    = dbase + l16;
        const float bv = bf2f(bias[col]);
        const bool rope = (dbase == 0) && (slot != 5);
#pragma unroll
        for (int i = 0; i < 4; i++) {
            const int trow = bm + i * 16 + quad * 4;
#pragma unroll
            for (int r = 0; r < 4; r++) {
                float v = acc[i][j][r] + bv;
                float outv = v;
                if (rope) {
                    float part = __shfl_xor(v, 8, 64);
                    float rot = (l16 < 8) ? -part : part;
                    float cc = bf2f(ccos[(trow + r) * ROPE_N + l16]);
                    float ss = bf2f(csin[(trow + r) * ROPE_N + l16]);
                    outv = v * cc + rot * ss;
                }
                const int t = trow + r;
                if (slot < 4) {
                    int hh = g * 4 + slot;
                    Qout[((size_t)hh * T_SEQ + t) * 64 + d] = f2bf(outv * 0.125f);
                } else if (slot == 4) {
                    Kout[((size_t)g * T_SEQ + t) * 64 + d] = f2bf(outv);
                } else {
                    Vtout[((size_t)g * 64 + d) * T_SEQ + t] = f2bf(outv);
                }
            }
        }
    }
}

// ---------------------------------------------------------------------------
// GEMM2: out = A @ W^T + bias (bf16 in); store fp32/bf16 per flag.
// Same single-barrier register-pipelined structure.
// ---------------------------------------------------------------------------
__global__ __launch_bounds__(256) void gemm_bt(
    const u16* __restrict__ A, const u16* __restrict__ W,
    const u16* __restrict__ bias, u16* __restrict__ Cout,
    int M, int N, int K, const int* __restrict__ flag)
{
    __shared__ __attribute__((aligned(16))) u16 lds_a[2][64 * GS];
    __shared__ __attribute__((aligned(16))) u16 lds_b[2][128 * GS];

    const int tid  = threadIdx.x;
    const int wave = tid >> 6;
    const int lane = tid & 63;
    const int quad = lane >> 4;
    const int l16  = lane & 15;
    const int bm = blockIdx.y * 64;
    const int bn = blockIdx.x * 128;
    const int fl = *flag;

    f32x4 acc[4][2] = {};

    const int ra = tid >> 2, ca = (tid & 3) * 8;
    const int rb1 = ra + 64;

    int4 ap, bp0, bp1;
    auto load_tile = [&](int k0) {
        ap  = *(const int4*)(A + (size_t)(bm + ra) * K + k0 + ca);
        bp0 = *(const int4*)(W + (size_t)(bn + ra) * K + k0 + ca);
        bp1 = *(const int4*)(W + (size_t)(bn + rb1) * K + k0 + ca);
    };

    load_tile(0);
    const int nsteps = K / 32;
    for (int kt = 0; kt < nsteps; kt++) {
        const int p = kt & 1;
        *(int4*)(lds_a[p] + ra * GS + ca)  = ap;
        *(int4*)(lds_b[p] + ra * GS + ca)  = bp0;
        *(int4*)(lds_b[p] + rb1 * GS + ca) = bp1;
        __syncthreads();
        if (kt + 1 < nsteps) load_tile((kt + 1) * 32);

        bf16x8 afr[4], bfr[2];
#pragma unroll
        for (int i = 0; i < 4; i++)
            afr[i] = *(const bf16x8*)(lds_a[p] + (i * 16 + l16) * GS + quad * 8);
#pragma unroll
        for (int j = 0; j < 2; j++)
            bfr[j] = *(const bf16x8*)(lds_b[p] + (wave * 32 + j * 16 + l16) * GS + quad * 8);
#pragma unroll
        for (int i = 0; i < 4; i++)
#pragma unroll
            for (int j = 0; j < 2; j++)
                acc[i][j] = __builtin_amdgcn_mfma_f32_16x16x32_bf16(afr[i], bfr[j], acc[i][j], 0, 0, 0);
    }

#pragma unroll
    for (int i = 0; i < 4; i++) {
        int row = bm + i * 16 + quad * 4;
#pragma unroll
        for (int j = 0; j < 2; j++) {
            int col = bn + wave * 32 + j * 16 + l16;
            float bv = bf2f(bias[col]);
#pragma unroll
            for (int r = 0; r < 4; r++) {
                float v = acc[i][j][r] + bv;
                size_t idx = (size_t)(row + r) * N + col;
                if (fl) ((float*)Cout)[idx] = v;
                else    Cout[idx] = f2bf(v);
            }
        }
    }
}

// ---------------------------------------------------------------------------
// Flash attention: fixed-max softmax, diagonal-only masking, LDS-dbuf K/Vt
// with register prefetch. Grid (16,32): block bx does q-tiles {bx, 31-bx}.
// ---------------------------------------------------------------------------
__global__ __launch_bounds__(256) void flash_attn(
    const u16* __restrict__ Q, const u16* __restrict__ K,
    const u16* __restrict__ Vt, u16* __restrict__ Y)
{
    __shared__ __attribute__((aligned(16))) u16 lds_q[64 * LS];
    __shared__ __attribute__((aligned(16))) u16 lds_k[2][64 * LS];
    __shared__ __attribute__((aligned(16))) u16 lds_vt[2][64 * LS];
    __shared__ __attribute__((aligned(16))) u16 lds_p[4][16 * LS];

    const int h  = blockIdx.y;
    const int g  = h >> 2;
    const int tid  = threadIdx.x;
    const int wave = tid >> 6;
    const int lane = tid & 63;
    const int quad = lane >> 4;
    const int l16  = lane & 15;
    const int NQT = T_SEQ / 64;

    const u16* Qh = Q  + (size_t)h * T_SEQ * 64;
    const u16* Kg = K  + (size_t)g * T_SEQ * 64;
    const u16* Vg = Vt + (size_t)g * 64 * T_SEQ;   // [d][T]

    const int srow = tid >> 3, scc = (tid & 7) * 8;

    int4 kr0, kr1, vr0, vr1;
    auto load_tile = [&](int k0) {
        kr0 = *(const int4*)(Kg + (size_t)(k0 + srow) * 64 + scc);
        kr1 = *(const int4*)(Kg + (size_t)(k0 + srow + 32) * 64 + scc);
        vr0 = *(const int4*)(Vg + (size_t)srow * T_SEQ + k0 + scc);
        vr1 = *(const int4*)(Vg + (size_t)(srow + 32) * T_SEQ + k0 + scc);
    };

    for (int pass = 0; pass < 2; pass++) {
        const int qt = pass ? (NQT - 1 - blockIdx.x) : blockIdx.x;
        const int q0 = qt * 64;

        __syncthreads();
        for (int s = tid; s < 512; s += 256) {
            int row = s >> 3, cc = (s & 7) * 8;
            *(int4*)(lds_q + row * LS + cc) =
                *(const int4*)(Qh + (size_t)(q0 + row) * 64 + cc);
        }
        __syncthreads();

        bf16x8 a_q[2];
#pragma unroll
        for (int ks = 0; ks < 2; ks++)
            a_q[ks] = *(const bf16x8*)(lds_q + (wave * 16 + l16) * LS + ks * 32 + quad * 8);

        float rs[4] = {0.f, 0.f, 0.f, 0.f};
        f32x4 o_acc[4] = {};

        load_tile(0);

        for (int kt = 0; kt <= qt; kt++) {
            const int p = kt & 1;
            *(int4*)(lds_k[p]  + srow * LS + scc)        = kr0;
            *(int4*)(lds_k[p]  + (srow + 32) * LS + scc) = kr1;
            *(int4*)(lds_vt[p] + srow * LS + scc)        = vr0;
            *(int4*)(lds_vt[p] + (srow + 32) * LS + scc) = vr1;
            __syncthreads();
            if (kt < qt) load_tile((kt + 1) * 64);

            f32x4 sc[4] = {};
#pragma unroll
            for (int ks = 0; ks < 2; ks++)
#pragma unroll
                for (int t = 0; t < 4; t++) {
                    bf16x8 bk = *(const bf16x8*)(lds_k[p] + (t * 16 + l16) * LS + ks * 32 + quad * 8);
                    sc[t] = __builtin_amdgcn_mfma_f32_16x16x32_bf16(a_q[ks], bk, sc[t], 0, 0, 0);
                }

            if (kt == qt) {
                const int row_g = q0 + wave * 16 + quad * 4;
                const int k0 = kt * 64;
#pragma unroll
                for (int t = 0; t < 4; t++) {
                    int col_g = k0 + t * 16 + l16;
#pragma unroll
                    for (int r = 0; r < 4; r++)
                        if (col_g > row_g + r) sc[t][r] = NEG_BIG;
                }
            }

#pragma unroll
            for (int t = 0; t < 4; t++) {
                int colo = t * 16 + l16;
#pragma unroll
                for (int r = 0; r < 4; r++) {
                    float pv = __expf(sc[t][r]);
                    rs[r] += pv;
                    lds_p[wave][(quad * 4 + r) * LS + colo] = f2bf(pv);
                }
            }
            __syncthreads();

#pragma unroll
            for (int ks = 0; ks < 2; ks++) {
                bf16x8 apf = *(const bf16x8*)(lds_p[wave] + l16 * LS + ks * 32 + quad * 8);
#pragma unroll
                for (int t = 0; t < 4; t++) {
                    bf16x8 bvf = *(const bf16x8*)(lds_vt[p] + (t * 16 + l16) * LS + ks * 32 + quad * 8);
                    o_acc[t] = __builtin_amdgcn_mfma_f32_16x16x32_bf16(apf, bvf, o_acc[t], 0, 0, 0);
                }
            }
        }

#pragma unroll
        for (int off = 1; off < 16; off <<= 1)
#pragma unroll
            for (int r = 0; r < 4; r++)
                rs[r] += __shfl_xor(rs[r], off, 64);

#pragma unroll
        for (int t = 0; t < 4; t++)
#pragma unroll
            for (int r = 0; r < 4; r++) {
                int row = q0 + wave * 16 + quad * 4 + r;
                int d   = t * 16 + l16;
                Y[(size_t)row * (N_HEAD * HEAD_SIZE) + h * 64 + d] = f2bf(o_acc[t][r] / rs[r]);
            }
    }
}

// ---------------------------------------------------------------------------
extern "C" void kernel_launch(void* const* d_in, const int* in_sizes, int n_in,
                              void* d_out, int out_size, void* d_ws, size_t ws_size,
                              hipStream_t stream)
{
    int* flag = (int*)d_ws;
    u16* base = (u16*)d_ws + 8;

    u16* cx   = base;                                      // 2048*2048
    u16* cWa  = cx  + (size_t)T_SEQ * C_DIM;               // 3072*2048
    u16* cba  = cWa + (size_t)QKV_DIM * C_DIM;             // 3072
    u16* cWp  = cba + QKV_DIM;                             // 2048*2048
    u16* cbp  = cWp + (size_t)C_DIM * C_DIM;               // 2048
    u16* ccos = cbp + C_DIM;                               // 2048*16
    u16* csin = ccos + (size_t)T_SEQ * ROPE_N;             // 2048*16
    u16* Qb   = csin + (size_t)T_SEQ * ROPE_N;             // 32*2048*64
    u16* Kb   = Qb + (size_t)N_HEAD * T_SEQ * HEAD_SIZE;   // 8*2048*64
    u16* Vtb  = Kb + (size_t)N_GROUPS * T_SEQ * HEAD_SIZE; // 8*64*2048 (transposed)
    u16* Yb   = Vtb + (size_t)N_GROUPS * T_SEQ * HEAD_SIZE;// 2048*2048

    dim3 blk(256);

    detect_dtype<<<1, blk, 0, stream>>>((const u16*)d_in[0], flag);

    ConvDesc cd;
    const int sizes[7] = { T_SEQ * C_DIM, T_SEQ * ROPE_N, T_SEQ * ROPE_N,
                           QKV_DIM * C_DIM, QKV_DIM, C_DIM * C_DIM, C_DIM };
    u16* dsts[7] = { cx, ccos, csin, cWa, cba, cWp, cbp };
    int acc8 = 0;
    for (int i = 0; i < 7; i++) {
        cd.src[i] = d_in[i];
        cd.dst[i] = dsts[i];
        cd.off8[i] = acc8;
        acc8 += sizes[i] / 8;
    }
    cd.off8[7] = acc8;
    convert_all<<<dim3((acc8 + 255) / 256), blk, 0, stream>>>(cd, flag);

    gemm_qkv_rope<<<dim3(QKV_DIM / 128, T_SEQ / 64), blk, 0, stream>>>(
        cx, cWa, cba, ccos, csin, Qb, Kb, Vtb);
    flash_attn<<<dim3(T_SEQ / 128, N_HEAD), blk, 0, stream>>>(Qb, Kb, Vtb, Yb);
    gemm_bt<<<dim3(C_DIM / 128, T_SEQ / 64), blk, 0, stream>>>(
        Yb, cWp, cbp, (u16*)d_out, T_SEQ, C_DIM, N_HEAD * HEAD_SIZE, flag);
}